// Round 6
// baseline (615.425 us; speedup 1.0000x reference)
//
#include <hip/hip_runtime.h>
#include <hip/hip_cooperative_groups.h>

namespace cg = cooperative_groups;

#define BB 4096
#define TT 750
#define NS_STRIDE 768
#define NBLK 768           // 768 interior tiles; edge pairs folded into blocks 0..123
#define NRED 33            // phase-2 active blocks (33*256 = 8448 = 11*768)

// ws float offsets (total < 2.2 MB)
#define NSP_OFF   0                        // 8448*64 transposed interior partials
#define EDGE_OFF  (8448 * 64)              // 124 edge partials (31 pairs x 4 chunks)
#define ENS_OFF   (EDGE_OFF + 128)         // 8448 = exp(-ns/2), layout [k][t] stride 768
#define FLAG_OFF  (ENS_OFF + 8448)         // 33 ints: per-phase2-block "any ens>0"
#define SLOT_OFF  (FLAG_OFF + 64)          // 768 per-phase3-block partial sums

// ============ phase 1: ns partials (two 32-row halves) + folded edge pairs ============
__device__ __forceinline__ void phase1(const float* __restrict__ a,
                                       float* __restrict__ ns_p,
                                       float* __restrict__ edge_c,
                                       int b, int tid) {
    __shared__ float smem[2816];     // halves: tile 32x76 = 2432 ; then red 4x704 = 2816
    __shared__ float swred[4];
    const int x = b % 12, y = b / 12;
    const int t0 = x * 64, i0 = y * 64;
    const int tl = tid & 63, ig = tid >> 6;
    const bool interior = (x >= 1 && x <= 10);

    float acc[11];
#pragma unroll
    for (int k = 0; k < 11; ++k) acc[k] = 0.f;

    for (int h = 0; h < 2; ++h) {
        for (int l = tid; l < 32 * 74; l += 256) {
            int r = l / 74, c = l - r * 74;
            int gc = t0 - 6 + c;
            float v = 0.f;
            if (gc >= 0 && gc < TT) v = a[(i0 + h * 32 + r) * TT + gc];
            smem[r * 76 + c] = v;
        }
        __syncthreads();
        if (interior) {
            for (int r = ig; r < 32; r += 4) {
                float xx = smem[r * 76 + tl + 6];
#pragma unroll
                for (int k = 0; k < 11; ++k) {
                    float d = xx - smem[r * 76 + tl + k];
                    acc[k] += d * d;
                }
            }
        } else {
            const int t = t0 + tl;
            if (t < TT) {
                for (int r = ig; r < 32; r += 4) {
                    float xx = smem[r * 76 + tl + 6];
#pragma unroll
                    for (int k = 0; k < 11; ++k) {
                        int q = t + k - 6;
                        float d = xx - smem[r * 76 + tl + k];
                        if (q >= 0 && q < TT) acc[k] += d * d;
                    }
                }
            }
        }
        __syncthreads();   // tile reads done before next-half overwrite / red aliasing
    }

    // red aliases smem: red[ig][l], l = tl*11 + k  (stride-11 mod 32 banks -> 2-way, free)
#pragma unroll
    for (int k = 0; k < 11; ++k) smem[ig * 704 + tl * 11 + k] = acc[k];
    __syncthreads();

    // transposed store: ns_p[(x*704 + l)*64 + y]
    for (int l = tid; l < 704; l += 256) {
        float s = smem[l] + smem[704 + l] + smem[1408 + l] + smem[2112 + l];
        ns_p[(size_t)(x * 704 + l) * 64 + y] = s;
    }

    // folded edge work: blocks 0..123 -> pair q = b>>2, i-chunk ch = b&3
    if (b < 124) {
        const int q = b >> 2, ch = b & 3;
        int t = 0, k = 0;
        if (q < 21) {                       // front: t+k < 6, t-major
            int idx = q;
            for (int tt = 0; tt < 6; ++tt) {
                int c = 6 - tt;
                if (idx < c) { t = tt; k = idx; break; }
                idx -= c;
            }
        } else {                            // back: t+k >= 756
            int idx = q - 21;
            for (int tt = 746; tt < 750; ++tt) {
                int c = tt - 745;
                if (idx < c) { t = tt; k = (11 - c) + idx; break; }
                idx -= c;
            }
        }
        const int p = t + k;                // block-uniform
        float s = 0.f;
        int i = ch * 1024 + tid;
#pragma unroll
        for (int it = 0; it < 4; ++it, i += 256) {
            float xv = a[i * TT + t];
            float v = (p < 6) ? a[((6 * i + p) & (BB - 1)) * TT]
                              : a[((6 * i + (p - 755)) & (BB - 1)) * TT + (TT - 1)];
            float d = xv - v;
            s += d * d;
        }
        for (int off = 32; off > 0; off >>= 1) s += __shfl_down(s, off, 64);
        if ((tid & 63) == 0) swred[tid >> 6] = s;
        __syncthreads();
        if (tid == 0)
            edge_c[q * 4 + ch] = swred[0] + swred[1] + swred[2] + swred[3];
    }
}

// ============ phase 2: reduce 64 y-partials (float4) + edge, exp, flags ============
__device__ __forceinline__ void phase2(const float* __restrict__ ns_p,
                                       const float* __restrict__ edge_c,
                                       float* __restrict__ ens,
                                       int* __restrict__ flags,
                                       int b, int tid) {
    __shared__ int swf[4];
    const int l = b * 256 + tid;
    const int k = l / NS_STRIDE;
    const int t = l - k * NS_STRIDE;
    float e = 0.f;
    if (t < TT) {
        const int idx2 = (t >> 6) * 704 + (t & 63) * 11 + k;
        const float4* pp4 = (const float4*)(ns_p + (size_t)idx2 * 64);
        float s = 0.f;
#pragma unroll
        for (int j = 0; j < 16; ++j) {
            float4 v = pp4[j];
            s += v.x + v.y + v.z + v.w;
        }
        const int p = t + k;
        if (p < 6 || p >= 756) {
            int idx = (p < 6) ? (t * 6 - t * (t - 1) / 2 + k)
                              : (21 + (t - 746) * (t - 745) / 2 + (k - (756 - t)));
            s += edge_c[idx * 4 + 0] + edge_c[idx * 4 + 1] +
                 edge_c[idx * 4 + 2] + edge_c[idx * 4 + 3];
        }
        e = __expf(-0.5f * s);
    }
    ens[l] = e;
    unsigned long long anyb = __ballot(e > 0.f);
    if ((tid & 63) == 0) swf[tid >> 6] = (anyb != 0ull);
    __syncthreads();
    if (tid == 0) flags[b] = swf[0] | swf[1] | swf[2] | swf[3];
}

// ============ phase 3: main loss (16 i's per block, one slot per block) ============
__device__ __forceinline__ void phase3(const float* __restrict__ a,
                                       const float* __restrict__ a2,
                                       const float* __restrict__ ens,
                                       const int* __restrict__ flags,
                                       float* __restrict__ slots,
                                       int b, int tid) {
    __shared__ float s_a4[268];
    __shared__ float s_a3[268];
    __shared__ float swred[4];
    const int x = b % 3;            // t-chunk
    const int y = b / 3;            // i-group
    const int t0 = x * 256;
    const int t = t0 + tid;

    int flag = 0;
    for (int j = 0; j < NRED; ++j) flag |= flags[j];   // uniform, L2-hot

    float partial = 0.f;
    if (flag == 0) {
        // all ens == 0 -> min(ens,eg)*d2 == 0: only the reg term survives (data-driven)
        if (t < TT) {
            float s = 0.f;
#pragma unroll
            for (int ii = 0; ii < 16; ++ii) {
                int i = y * 16 + ii;
                float d = a[i * TT + t] - a2[i * TT + t];
                s += d * d;
            }
            partial = 0.1f * s;                        // E_THETA
        }
    } else {
        for (int ii = 0; ii < 16; ++ii) {
            const int i = y * 16 + ii;
            __syncthreads();
            for (int c = tid; c < 266; c += 256) {
                int p = t0 + c;
                float v4, v3;
                if (p < 6) {
                    int r = (6 * i + p) & (BB - 1);
                    v4 = a[r * TT];
                    v3 = a2[r * TT];
                } else if (p < 756) {
                    v4 = a[i * TT + p - 6];
                    v3 = a2[i * TT + p - 6];
                } else {
                    int r = (6 * i + (p - 755)) & (BB - 1);
                    v4 = a[r * TT + (TT - 1)];
                    v3 = a2[r * TT + (TT - 1)];
                }
                s_a4[c] = v4;
                s_a3[c] = v3;
            }
            __syncthreads();
            if (t < TT) {
                const float s1 = s_a4[tid + 6];
                const float s2 = s_a3[tid + 6];
                float mw = -1e30f;
                float acc_d[11], acc_e[11];
#pragma unroll
                for (int k = 0; k < 11; ++k) {
                    float a4v = s_a4[tid + k];
                    float a3v = s_a3[tid + k];
                    int rr = (11 * i + k) & (BB - 1);
                    float tv = a[rr * TT + t];
                    mw = fmaxf(mw, tv - a4v);
                    acc_d[k] = fabsf(s2 - a3v);
                    acc_e[k] = ens[k * NS_STRIDE + t];
                }
                float g = mw * mw;                     // E_G
                float eg = __expf(-0.5f * g);          // SIGMA
                float acc = 0.f;
#pragma unroll
                for (int k = 0; k < 11; ++k) acc += fminf(acc_e[k], eg) * acc_d[k];
                float diff = s1 - s2;
                partial += acc + 0.1f * diff * diff;
            }
        }
    }

    for (int off = 32; off > 0; off >>= 1) partial += __shfl_down(partial, off, 64);
    if ((tid & 63) == 0) swred[tid >> 6] = partial;
    __syncthreads();
    if (tid == 0)
        slots[b] = swred[0] + swred[1] + swred[2] + swred[3];   // plain store
}

// ============ phase 4: final reduce ============
__device__ __forceinline__ void phase4(const float* __restrict__ slots,
                                       float* __restrict__ out, int tid) {
    __shared__ float fred[4];
    float v = slots[tid] + slots[tid + 256] + slots[tid + 512];
    for (int off = 32; off > 0; off >>= 1) v += __shfl_down(v, off, 64);
    if ((tid & 63) == 0) fred[tid >> 6] = v;
    __syncthreads();
    if (tid == 0)
        out[0] = (fred[0] + fred[1] + fred[2] + fred[3]) * (1.0f / BB);  // E_ALPHA
}

// ============ cooperative mega-kernel ============
__global__ __launch_bounds__(256, 4) void k_all(const float* __restrict__ a,
                                                const float* __restrict__ a2,
                                                float* __restrict__ ws,
                                                float* __restrict__ out) {
    float* ns_p   = ws + NSP_OFF;
    float* edge_c = ws + EDGE_OFF;
    float* ens    = ws + ENS_OFF;
    int*   flags  = (int*)(ws + FLAG_OFF);
    float* slots  = ws + SLOT_OFF;
    const int b = blockIdx.x, tid = threadIdx.x;
    cg::grid_group grid = cg::this_grid();

    phase1(a, ns_p, edge_c, b, tid);
    __threadfence();
    grid.sync();
    if (b < NRED) phase2(ns_p, edge_c, ens, flags, b, tid);
    __threadfence();
    grid.sync();
    phase3(a, a2, ens, flags, slots, b, tid);
    __threadfence();
    grid.sync();
    if (b == 0) phase4(slots, out, tid);
}

// ============ fallback: identical phases as 4 regular dispatches ============
__global__ __launch_bounds__(256, 4) void k1f(const float* __restrict__ a,
                                              float* __restrict__ ns_p,
                                              float* __restrict__ edge_c) {
    phase1(a, ns_p, edge_c, blockIdx.x, threadIdx.x);
}
__global__ __launch_bounds__(256) void k2f(const float* __restrict__ ns_p,
                                           const float* __restrict__ edge_c,
                                           float* __restrict__ ens,
                                           int* __restrict__ flags) {
    phase2(ns_p, edge_c, ens, flags, blockIdx.x, threadIdx.x);
}
__global__ __launch_bounds__(256, 4) void k3f(const float* __restrict__ a,
                                              const float* __restrict__ a2,
                                              const float* __restrict__ ens,
                                              const int* __restrict__ flags,
                                              float* __restrict__ slots) {
    phase3(a, a2, ens, flags, slots, blockIdx.x, threadIdx.x);
}
__global__ __launch_bounds__(256) void k4f(const float* __restrict__ slots,
                                           float* __restrict__ out) {
    phase4(slots, out, threadIdx.x);
}

extern "C" void kernel_launch(void* const* d_in, const int* in_sizes, int n_in,
                              void* d_out, int out_size, void* d_ws, size_t ws_size,
                              hipStream_t stream) {
    const float* a  = (const float*)d_in[0];   // actioness
    const float* a2 = (const float*)d_in[1];   // actioness_2
    float* ws  = (float*)d_ws;
    float* out = (float*)d_out;

    void* args[] = { (void*)&a, (void*)&a2, (void*)&ws, (void*)&out };
    hipError_t err = hipLaunchCooperativeKernel((const void*)k_all, dim3(NBLK), dim3(256),
                                                args, 0, stream);
    if (err != hipSuccess) {
        (void)hipGetLastError();   // clear sticky error, use proven 4-dispatch path
        float* ns_p   = ws + NSP_OFF;
        float* edge_c = ws + EDGE_OFF;
        float* ens    = ws + ENS_OFF;
        int*   flags  = (int*)(ws + FLAG_OFF);
        float* slots  = ws + SLOT_OFF;
        k1f<<<NBLK, 256, 0, stream>>>(a, ns_p, edge_c);
        k2f<<<NRED, 256, 0, stream>>>(ns_p, edge_c, ens, flags);
        k3f<<<NBLK, 256, 0, stream>>>(a, a2, ens, flags, slots);
        k4f<<<1, 256, 0, stream>>>(slots, out);
    }
}

// Round 7
// 212.277 us; speedup vs baseline: 2.8992x; 2.8992x over previous
//
#include <hip/hip_runtime.h>

#define BB 4096
#define TT 750
#define NS_STRIDE 768
#define NBLK 768           // 768 interior tiles; edge pairs folded into blocks 0..123
#define NRED 33            // phase-2 producer blocks (33*256 = 8448 = 11*768)

// ws float offsets (total < 2.2 MB)
#define NSP_OFF   0                        // 8448*64 transposed interior partials
#define EDGE_OFF  (8448 * 64)              // 124 edge partials (31 pairs x 4 chunks)
#define ENS_OFF   (EDGE_OFF + 128)         // 8448 = exp(-ns/2), layout [k][t] stride 768
#define SLOT_OFF  (ENS_OFF + 8448)         // 768 per-phase3-block partial sums
#define CTRL_OFF  (SLOT_OFF + 768)         // 3 ints: p2done, gflag, p3done

// ============ phase 1: ns partials (two 32-row halves) + folded edge pairs ============
// verified correct in R6 run (absmax 0.0)
__device__ __forceinline__ void phase1(const float* __restrict__ a,
                                       float* __restrict__ ns_p,
                                       float* __restrict__ edge_c,
                                       int b, int tid) {
    __shared__ float smem[2816];     // halves: tile 32x76 = 2432 ; then red 4x704 = 2816
    __shared__ float swred[4];
    const int x = b % 12, y = b / 12;
    const int t0 = x * 64, i0 = y * 64;
    const int tl = tid & 63, ig = tid >> 6;
    const bool interior = (x >= 1 && x <= 10);

    float acc[11];
#pragma unroll
    for (int k = 0; k < 11; ++k) acc[k] = 0.f;

    for (int h = 0; h < 2; ++h) {
        for (int l = tid; l < 32 * 74; l += 256) {
            int r = l / 74, c = l - r * 74;
            int gc = t0 - 6 + c;
            float v = 0.f;
            if (gc >= 0 && gc < TT) v = a[(i0 + h * 32 + r) * TT + gc];
            smem[r * 76 + c] = v;
        }
        __syncthreads();
        if (interior) {
            for (int r = ig; r < 32; r += 4) {
                float xx = smem[r * 76 + tl + 6];
#pragma unroll
                for (int k = 0; k < 11; ++k) {
                    float d = xx - smem[r * 76 + tl + k];
                    acc[k] += d * d;
                }
            }
        } else {
            const int t = t0 + tl;
            if (t < TT) {
                for (int r = ig; r < 32; r += 4) {
                    float xx = smem[r * 76 + tl + 6];
#pragma unroll
                    for (int k = 0; k < 11; ++k) {
                        int q = t + k - 6;
                        float d = xx - smem[r * 76 + tl + k];
                        if (q >= 0 && q < TT) acc[k] += d * d;
                    }
                }
            }
        }
        __syncthreads();   // tile reads done before next-half overwrite / red aliasing
    }

#pragma unroll
    for (int k = 0; k < 11; ++k) smem[ig * 704 + tl * 11 + k] = acc[k];
    __syncthreads();

    // transposed store: ns_p[(x*704 + l)*64 + y]
    for (int l = tid; l < 704; l += 256) {
        float s = smem[l] + smem[704 + l] + smem[1408 + l] + smem[2112 + l];
        ns_p[(size_t)(x * 704 + l) * 64 + y] = s;
    }

    // folded edge work: blocks 0..123 -> pair q = b>>2, i-chunk ch = b&3
    if (b < 124) {
        const int q = b >> 2, ch = b & 3;
        int t = 0, k = 0;
        if (q < 21) {                       // front: t+k < 6, t-major
            int idx = q;
            for (int tt = 0; tt < 6; ++tt) {
                int c = 6 - tt;
                if (idx < c) { t = tt; k = idx; break; }
                idx -= c;
            }
        } else {                            // back: t+k >= 756
            int idx = q - 21;
            for (int tt = 746; tt < 750; ++tt) {
                int c = tt - 745;
                if (idx < c) { t = tt; k = (11 - c) + idx; break; }
                idx -= c;
            }
        }
        const int p = t + k;                // block-uniform
        float s = 0.f;
        int i = ch * 1024 + tid;
#pragma unroll
        for (int it = 0; it < 4; ++it, i += 256) {
            float xv = a[i * TT + t];
            float v = (p < 6) ? a[((6 * i + p) & (BB - 1)) * TT]
                              : a[((6 * i + (p - 755)) & (BB - 1)) * TT + (TT - 1)];
            float d = xv - v;
            s += d * d;
        }
        for (int off = 32; off > 0; off >>= 1) s += __shfl_down(s, off, 64);
        if ((tid & 63) == 0) swred[tid >> 6] = s;
        __syncthreads();
        if (tid == 0)
            edge_c[q * 4 + ch] = swred[0] + swred[1] + swred[2] + swred[3];
    }
}

// ============ phase 2: reduce 64 y-partials (float4) + edge, exp; returns block flag ====
__device__ __forceinline__ int phase2(const float* __restrict__ ns_p,
                                      const float* __restrict__ edge_c,
                                      float* __restrict__ ens,
                                      int b, int tid) {
    __shared__ int swf[4];
    const int l = b * 256 + tid;
    const int k = l / NS_STRIDE;
    const int t = l - k * NS_STRIDE;
    float e = 0.f;
    if (t < TT) {
        const int idx2 = (t >> 6) * 704 + (t & 63) * 11 + k;
        const float4* pp4 = (const float4*)(ns_p + (size_t)idx2 * 64);
        float s = 0.f;
#pragma unroll
        for (int j = 0; j < 16; ++j) {
            float4 v = pp4[j];
            s += v.x + v.y + v.z + v.w;
        }
        const int p = t + k;
        if (p < 6 || p >= 756) {
            int idx = (p < 6) ? (t * 6 - t * (t - 1) / 2 + k)
                              : (21 + (t - 746) * (t - 745) / 2 + (k - (756 - t)));
            s += edge_c[idx * 4 + 0] + edge_c[idx * 4 + 1] +
                 edge_c[idx * 4 + 2] + edge_c[idx * 4 + 3];
        }
        e = __expf(-0.5f * s);
    }
    ens[l] = e;
    unsigned long long anyb = __ballot(e > 0.f);
    if ((tid & 63) == 0) swf[tid >> 6] = (anyb != 0ull);
    __syncthreads();
    return swf[0] | swf[1] | swf[2] | swf[3];
}

// ============ phase 3: main loss (16 i's per block); flag passed in ============
__device__ __forceinline__ void phase3(const float* __restrict__ a,
                                       const float* __restrict__ a2,
                                       const float* __restrict__ ens,
                                       int flag,
                                       float* __restrict__ slots,
                                       int b, int tid) {
    __shared__ float s_a4[268];
    __shared__ float s_a3[268];
    __shared__ float swred[4];
    const int x = b % 3;            // t-chunk
    const int y = b / 3;            // i-group
    const int t0 = x * 256;
    const int t = t0 + tid;

    float partial = 0.f;
    if (flag == 0) {
        // all ens == 0 -> min(ens,eg)*d2 == 0: only the reg term survives (data-driven)
        if (t < TT) {
            float s = 0.f;
#pragma unroll
            for (int ii = 0; ii < 16; ++ii) {
                int i = y * 16 + ii;
                float d = a[i * TT + t] - a2[i * TT + t];
                s += d * d;
            }
            partial = 0.1f * s;                        // E_THETA
        }
    } else {
        for (int ii = 0; ii < 16; ++ii) {
            const int i = y * 16 + ii;
            __syncthreads();
            for (int c = tid; c < 266; c += 256) {
                int p = t0 + c;
                float v4, v3;
                if (p < 6) {
                    int r = (6 * i + p) & (BB - 1);
                    v4 = a[r * TT];
                    v3 = a2[r * TT];
                } else if (p < 756) {
                    v4 = a[i * TT + p - 6];
                    v3 = a2[i * TT + p - 6];
                } else {
                    int r = (6 * i + (p - 755)) & (BB - 1);
                    v4 = a[r * TT + (TT - 1)];
                    v3 = a2[r * TT + (TT - 1)];
                }
                s_a4[c] = v4;
                s_a3[c] = v3;
            }
            __syncthreads();
            if (t < TT) {
                const float s1 = s_a4[tid + 6];
                const float s2 = s_a3[tid + 6];
                float mw = -1e30f;
                float acc_d[11], acc_e[11];
#pragma unroll
                for (int k = 0; k < 11; ++k) {
                    float a4v = s_a4[tid + k];
                    float a3v = s_a3[tid + k];
                    int rr = (11 * i + k) & (BB - 1);
                    float tv = a[rr * TT + t];
                    mw = fmaxf(mw, tv - a4v);
                    acc_d[k] = fabsf(s2 - a3v);
                    acc_e[k] = ens[k * NS_STRIDE + t];
                }
                float g = mw * mw;                     // E_G
                float eg = __expf(-0.5f * g);          // SIGMA
                float acc = 0.f;
#pragma unroll
                for (int k = 0; k < 11; ++k) acc += fminf(acc_e[k], eg) * acc_d[k];
                float diff = s1 - s2;
                partial += acc + 0.1f * diff * diff;
            }
        }
    }

    for (int off = 32; off > 0; off >>= 1) partial += __shfl_down(partial, off, 64);
    if ((tid & 63) == 0) swred[tid >> 6] = partial;
    __syncthreads();
    if (tid == 0)
        slots[b] = swred[0] + swred[1] + swred[2] + swred[3];   // plain store
}

// ============ phase 4: final reduce (run by the last-done block) ============
__device__ __forceinline__ void phase4(const float* __restrict__ slots,
                                       float* __restrict__ out, int tid) {
    __shared__ float fred[4];
    // agent-scope relaxed atomic loads: bypass stale cache copies cross-XCD
    float v = __hip_atomic_load(&slots[tid],       __ATOMIC_RELAXED, __HIP_MEMORY_SCOPE_AGENT)
            + __hip_atomic_load(&slots[tid + 256], __ATOMIC_RELAXED, __HIP_MEMORY_SCOPE_AGENT)
            + __hip_atomic_load(&slots[tid + 512], __ATOMIC_RELAXED, __HIP_MEMORY_SCOPE_AGENT);
    for (int off = 32; off > 0; off >>= 1) v += __shfl_down(v, off, 64);
    if ((tid & 63) == 0) fred[tid >> 6] = v;
    __syncthreads();
    if (tid == 0)
        out[0] = (fred[0] + fred[1] + fred[2] + fred[3]) * (1.0f / BB);  // E_ALPHA
}

// ============ node 1: phase1 + control-word init ============
__global__ __launch_bounds__(256, 4) void k_A(const float* __restrict__ a,
                                              float* __restrict__ ws) {
    float* ns_p   = ws + NSP_OFF;
    float* edge_c = ws + EDGE_OFF;
    int*   ctrl   = (int*)(ws + CTRL_OFF);
    phase1(a, ns_p, edge_c, blockIdx.x, threadIdx.x);
    if (blockIdx.x == 200 && threadIdx.x == 0) {
        ctrl[0] = 0;   // p2done
        ctrl[1] = 0;   // gflag
        ctrl[2] = 0;   // p3done
    }   // made device-visible by end-of-kernel release
}

// ============ node 2: phase2 (blocks 0..32) -> handshake -> phase3 -> last-block phase4 ==
__global__ __launch_bounds__(256, 4) void k_B(const float* __restrict__ a,
                                              const float* __restrict__ a2,
                                              float* __restrict__ ws,
                                              float* __restrict__ out) {
    float* ns_p   = ws + NSP_OFF;
    float* edge_c = ws + EDGE_OFF;
    float* ens    = ws + ENS_OFF;
    float* slots  = ws + SLOT_OFF;
    int*   ctrl   = (int*)(ws + CTRL_OFF);
    const int b = blockIdx.x, tid = threadIdx.x;

    if (b < NRED) {
        int bf = phase2(ns_p, edge_c, ens, b, tid);
        if (tid == 0) {
            atomicOr(&ctrl[1], bf);        // publish flag contribution
            __threadfence();               // release: ens + gflag before done-count
            atomicAdd(&ctrl[0], 1);
        }
    }

    // wait for all 33 producers (relaxed polls, single acquire fence after)
    __shared__ int sflag;
    if (tid == 0) {
        while (__hip_atomic_load(&ctrl[0], __ATOMIC_RELAXED, __HIP_MEMORY_SCOPE_AGENT) < NRED)
            __builtin_amdgcn_s_sleep(2);
        __threadfence();                   // acquire: ens/gflag now visible
        sflag = __hip_atomic_load(&ctrl[1], __ATOMIC_RELAXED, __HIP_MEMORY_SCOPE_AGENT);
    }
    __syncthreads();
    const int flag = sflag;

    phase3(a, a2, ens, flag, slots, b, tid);

    // last-done block performs the final reduction
    __threadfence();                       // release slots[b]
    __shared__ int lastArr;
    if (tid == 0) lastArr = atomicAdd(&ctrl[2], 1);
    __syncthreads();
    if (lastArr == NBLK - 1) {
        __threadfence();                   // acquire all slots
        phase4(slots, out, tid);
    }
}

extern "C" void kernel_launch(void* const* d_in, const int* in_sizes, int n_in,
                              void* d_out, int out_size, void* d_ws, size_t ws_size,
                              hipStream_t stream) {
    const float* a  = (const float*)d_in[0];   // actioness
    const float* a2 = (const float*)d_in[1];   // actioness_2
    float* ws  = (float*)d_ws;
    float* out = (float*)d_out;

    k_A<<<NBLK, 256, 0, stream>>>(a, ws);
    k_B<<<NBLK, 256, 0, stream>>>(a, a2, ws, out);
}

// Round 8
// 156.224 us; speedup vs baseline: 3.9394x; 1.3588x over previous
//
#include <hip/hip_runtime.h>

#define BB 4096
#define TT 750
#define NS_STRIDE 768
#define NBLK 768           // 768 interior tiles; edge pairs folded into blocks 0..123
#define NRED 33            // phase-2 blocks (33*256 = 8448 = 11*768)

// ws float offsets (total < 2.2 MB)
#define NSP_OFF   0                        // 8448*64 transposed interior partials
#define EDGE_OFF  (8448 * 64)              // 124 edge partials (31 pairs x 4 chunks)
#define ENS_OFF   (EDGE_OFF + 128)         // 8448 = exp(-ns/2), layout [k][t] stride 768
#define SLOT_OFF  (ENS_OFF + 8448)         // 768 per-phase3-block partial sums
#define FLAG_OFF  (SLOT_OFF + 768)         // 33 ints: per-phase2-block any(ens>0 && k!=6)
#define CTRL_OFF  (FLAG_OFF + 64)          // 1 int: p3done

// ============ phase 1: ns partials (two 32-row halves) + folded edge pairs ============
// verified R6/R7 (absmax 0.0)
__device__ __forceinline__ void phase1(const float* __restrict__ a,
                                       float* __restrict__ ns_p,
                                       float* __restrict__ edge_c,
                                       int b, int tid) {
    __shared__ float smem[2816];     // halves: tile 32x76 = 2432 ; then red 4x704 = 2816
    __shared__ float swred[4];
    const int x = b % 12, y = b / 12;
    const int t0 = x * 64, i0 = y * 64;
    const int tl = tid & 63, ig = tid >> 6;
    const bool interior = (x >= 1 && x <= 10);

    float acc[11];
#pragma unroll
    for (int k = 0; k < 11; ++k) acc[k] = 0.f;

    for (int h = 0; h < 2; ++h) {
        for (int l = tid; l < 32 * 74; l += 256) {
            int r = l / 74, c = l - r * 74;
            int gc = t0 - 6 + c;
            float v = 0.f;
            if (gc >= 0 && gc < TT) v = a[(i0 + h * 32 + r) * TT + gc];
            smem[r * 76 + c] = v;
        }
        __syncthreads();
        if (interior) {
            for (int r = ig; r < 32; r += 4) {
                float xx = smem[r * 76 + tl + 6];
#pragma unroll
                for (int k = 0; k < 11; ++k) {
                    float d = xx - smem[r * 76 + tl + k];
                    acc[k] += d * d;
                }
            }
        } else {
            const int t = t0 + tl;
            if (t < TT) {
                for (int r = ig; r < 32; r += 4) {
                    float xx = smem[r * 76 + tl + 6];
#pragma unroll
                    for (int k = 0; k < 11; ++k) {
                        int q = t + k - 6;
                        float d = xx - smem[r * 76 + tl + k];
                        if (q >= 0 && q < TT) acc[k] += d * d;
                    }
                }
            }
        }
        __syncthreads();   // tile reads done before next-half overwrite / red aliasing
    }

#pragma unroll
    for (int k = 0; k < 11; ++k) smem[ig * 704 + tl * 11 + k] = acc[k];
    __syncthreads();

    // transposed store: ns_p[(x*704 + l)*64 + y]
    for (int l = tid; l < 704; l += 256) {
        float s = smem[l] + smem[704 + l] + smem[1408 + l] + smem[2112 + l];
        ns_p[(size_t)(x * 704 + l) * 64 + y] = s;
    }

    // folded edge work: blocks 0..123 -> pair q = b>>2, i-chunk ch = b&3
    if (b < 124) {
        const int q = b >> 2, ch = b & 3;
        int t = 0, k = 0;
        if (q < 21) {                       // front: t+k < 6, t-major
            int idx = q;
            for (int tt = 0; tt < 6; ++tt) {
                int c = 6 - tt;
                if (idx < c) { t = tt; k = idx; break; }
                idx -= c;
            }
        } else {                            // back: t+k >= 756
            int idx = q - 21;
            for (int tt = 746; tt < 750; ++tt) {
                int c = tt - 745;
                if (idx < c) { t = tt; k = (11 - c) + idx; break; }
                idx -= c;
            }
        }
        const int p = t + k;                // block-uniform
        float s = 0.f;
        int i = ch * 1024 + tid;
#pragma unroll
        for (int it = 0; it < 4; ++it, i += 256) {
            float xv = a[i * TT + t];
            float v = (p < 6) ? a[((6 * i + p) & (BB - 1)) * TT]
                              : a[((6 * i + (p - 755)) & (BB - 1)) * TT + (TT - 1)];
            float d = xv - v;
            s += d * d;
        }
        for (int off = 32; off > 0; off >>= 1) s += __shfl_down(s, off, 64);
        if ((tid & 63) == 0) swred[tid >> 6] = s;
        __syncthreads();
        if (tid == 0)
            edge_c[q * 4 + ch] = swred[0] + swred[1] + swred[2] + swred[3];
    }
}

// ============ node 1: phase1 + control-word init ============
__global__ __launch_bounds__(256, 4) void k_A(const float* __restrict__ a,
                                              float* __restrict__ ws) {
    float* ns_p   = ws + NSP_OFF;
    float* edge_c = ws + EDGE_OFF;
    int*   ctrl   = (int*)(ws + CTRL_OFF);
    phase1(a, ns_p, edge_c, blockIdx.x, threadIdx.x);
    if (blockIdx.x == 200 && threadIdx.x == 0) ctrl[0] = 0;   // p3done
}

// ============ node 2: reduce 64 y-partials (float4) + edge, exp, per-block k!=6 flag ====
// KEY FIX vs R2-R7: ns[t,6] == 0 structurally (window center) -> ens[t,6] == 1 always.
// But d2[:,:,6] == |a2[i,t]-a2[i,t]| == 0 structurally too, so k=6 can NEVER contribute.
// The skip condition must therefore exclude k==6 -- with that, the fast path is reachable.
__global__ __launch_bounds__(256) void k_B(const float* __restrict__ ws_ro,
                                           float* __restrict__ ws) {
    const float* ns_p   = ws_ro + NSP_OFF;
    const float* edge_c = ws_ro + EDGE_OFF;
    float* ens   = ws + ENS_OFF;
    int*   flags = (int*)(ws + FLAG_OFF);
    __shared__ int swf[4];
    const int b = blockIdx.x, tid = threadIdx.x;
    const int l = b * 256 + tid;
    const int k = l / NS_STRIDE;
    const int t = l - k * NS_STRIDE;
    float e = 0.f;
    if (t < TT) {
        const int idx2 = (t >> 6) * 704 + (t & 63) * 11 + k;
        const float4* pp4 = (const float4*)(ns_p + (size_t)idx2 * 64);
        float s = 0.f;
#pragma unroll
        for (int j = 0; j < 16; ++j) {
            float4 v = pp4[j];
            s += v.x + v.y + v.z + v.w;
        }
        const int p = t + k;
        if (p < 6 || p >= 756) {
            int idx = (p < 6) ? (t * 6 - t * (t - 1) / 2 + k)
                              : (21 + (t - 746) * (t - 745) / 2 + (k - (756 - t)));
            s += edge_c[idx * 4 + 0] + edge_c[idx * 4 + 1] +
                 edge_c[idx * 4 + 2] + edge_c[idx * 4 + 3];
        }
        e = __expf(-0.5f * s);
    }
    ens[l] = e;
    unsigned long long anyb = __ballot(e > 0.f && k != 6);
    if ((tid & 63) == 0) swf[tid >> 6] = (anyb != 0ull);
    __syncthreads();
    if (tid == 0) flags[b] = swf[0] | swf[1] | swf[2] | swf[3];
}

// ============ node 3: main loss (16 i's per block) + last-block final reduce ============
__global__ __launch_bounds__(256, 4) void k_C(const float* __restrict__ a,
                                              const float* __restrict__ a2,
                                              float* __restrict__ ws,
                                              float* __restrict__ out) {
    const float* ens   = ws + ENS_OFF;
    const int*   flags = (const int*)(ws + FLAG_OFF);
    float* slots = ws + SLOT_OFF;
    int*   ctrl  = (int*)(ws + CTRL_OFF);
    __shared__ float s_a4[268];
    __shared__ float s_a3[268];
    __shared__ float swred[4];
    const int b = blockIdx.x, tid = threadIdx.x;
    const int x = b % 3;            // t-chunk
    const int y = b / 3;            // i-group
    const int t0 = x * 256;
    const int t = t0 + tid;

    int flag = 0;
    for (int j = 0; j < NRED; ++j) flag |= flags[j];   // uniform, cross-kernel visible

    float partial = 0.f;
    if (flag == 0) {
        // all ens (k!=6) are zero; k=6 term is structurally zero -> only the reg term
        if (t < TT) {
            float s = 0.f;
#pragma unroll
            for (int ii = 0; ii < 16; ++ii) {
                int i = y * 16 + ii;
                float d = a[i * TT + t] - a2[i * TT + t];
                s += d * d;
            }
            partial = 0.1f * s;                        // E_THETA
        }
    } else {
        // general path (verified R4-R7); its k=6 term multiplies d2==0, harmless
        for (int ii = 0; ii < 16; ++ii) {
            const int i = y * 16 + ii;
            __syncthreads();
            for (int c = tid; c < 266; c += 256) {
                int p = t0 + c;
                float v4, v3;
                if (p < 6) {
                    int r = (6 * i + p) & (BB - 1);
                    v4 = a[r * TT];
                    v3 = a2[r * TT];
                } else if (p < 756) {
                    v4 = a[i * TT + p - 6];
                    v3 = a2[i * TT + p - 6];
                } else {
                    int r = (6 * i + (p - 755)) & (BB - 1);
                    v4 = a[r * TT + (TT - 1)];
                    v3 = a2[r * TT + (TT - 1)];
                }
                s_a4[c] = v4;
                s_a3[c] = v3;
            }
            __syncthreads();
            if (t < TT) {
                const float s1 = s_a4[tid + 6];
                const float s2 = s_a3[tid + 6];
                float mw = -1e30f;
                float acc_d[11], acc_e[11];
#pragma unroll
                for (int k = 0; k < 11; ++k) {
                    float a4v = s_a4[tid + k];
                    float a3v = s_a3[tid + k];
                    int rr = (11 * i + k) & (BB - 1);
                    float tv = a[rr * TT + t];
                    mw = fmaxf(mw, tv - a4v);
                    acc_d[k] = fabsf(s2 - a3v);
                    acc_e[k] = ens[k * NS_STRIDE + t];
                }
                float g = mw * mw;                     // E_G
                float eg = __expf(-0.5f * g);          // SIGMA
                float acc = 0.f;
#pragma unroll
                for (int k = 0; k < 11; ++k) acc += fminf(acc_e[k], eg) * acc_d[k];
                float diff = s1 - s2;
                partial += acc + 0.1f * diff * diff;
            }
        }
    }

    for (int off = 32; off > 0; off >>= 1) partial += __shfl_down(partial, off, 64);
    if ((tid & 63) == 0) swred[tid >> 6] = partial;
    __syncthreads();
    if (tid == 0)
        slots[b] = swred[0] + swred[1] + swred[2] + swred[3];   // plain store

    // last-done block performs the final reduction (no spinning; verified in R7)
    __threadfence();                       // release slots[b]
    __shared__ int lastArr;
    if (tid == 0) lastArr = atomicAdd(&ctrl[0], 1);
    __syncthreads();
    if (lastArr == NBLK - 1) {
        __threadfence();                   // acquire all slots
        __shared__ float fred[4];
        float v = __hip_atomic_load(&slots[tid],       __ATOMIC_RELAXED, __HIP_MEMORY_SCOPE_AGENT)
                + __hip_atomic_load(&slots[tid + 256], __ATOMIC_RELAXED, __HIP_MEMORY_SCOPE_AGENT)
                + __hip_atomic_load(&slots[tid + 512], __ATOMIC_RELAXED, __HIP_MEMORY_SCOPE_AGENT);
        for (int off = 32; off > 0; off >>= 1) v += __shfl_down(v, off, 64);
        if ((tid & 63) == 0) fred[tid >> 6] = v;
        __syncthreads();
        if (tid == 0)
            out[0] = (fred[0] + fred[1] + fred[2] + fred[3]) * (1.0f / BB);  // E_ALPHA
    }
}

extern "C" void kernel_launch(void* const* d_in, const int* in_sizes, int n_in,
                              void* d_out, int out_size, void* d_ws, size_t ws_size,
                              hipStream_t stream) {
    const float* a  = (const float*)d_in[0];   // actioness
    const float* a2 = (const float*)d_in[1];   // actioness_2
    float* ws  = (float*)d_ws;
    float* out = (float*)d_out;

    k_A<<<NBLK, 256, 0, stream>>>(a, ws);
    k_B<<<NRED, 256, 0, stream>>>(ws, ws);
    k_C<<<NBLK, 256, 0, stream>>>(a, a2, ws, out);
}

// Round 9
// 94.153 us; speedup vs baseline: 6.5364x; 1.6593x over previous
//
#include <hip/hip_runtime.h>

#define BB 4096
#define TT 750
#define NS_STRIDE 768
#define NBLK 768           // 768 interior tiles; edge pairs folded into blocks 0..123
#define NRED 33            // phase-2 blocks (33*256 = 8448 = 11*768)

// ws float offsets (total < 2.2 MB)
#define NSP_OFF   0                        // 8448*64 transposed interior partials
#define EDGE_OFF  (8448 * 64)              // 124 edge partials (31 pairs x 4 chunks)
#define ENS_OFF   (EDGE_OFF + 128)         // 8448 = exp(-ns/2), layout [k][t] stride 768
#define SLOT_OFF  (ENS_OFF + 8448)         // 768 per-phase3-block partial sums
#define FLAG_OFF  (SLOT_OFF + 768)         // 33 ints: per-phase2-block any(ens>0 && k!=6)

// ============ phase 1: ns partials (two 32-row halves) + folded edge pairs ============
// verified R6/R7/R8 (absmax 0.0)
__device__ __forceinline__ void phase1(const float* __restrict__ a,
                                       float* __restrict__ ns_p,
                                       float* __restrict__ edge_c,
                                       int b, int tid) {
    __shared__ float smem[2816];     // halves: tile 32x76 = 2432 ; then red 4x704 = 2816
    __shared__ float swred[4];
    const int x = b % 12, y = b / 12;
    const int t0 = x * 64, i0 = y * 64;
    const int tl = tid & 63, ig = tid >> 6;
    const bool interior = (x >= 1 && x <= 10);

    float acc[11];
#pragma unroll
    for (int k = 0; k < 11; ++k) acc[k] = 0.f;

    for (int h = 0; h < 2; ++h) {
        for (int l = tid; l < 32 * 74; l += 256) {
            int r = l / 74, c = l - r * 74;
            int gc = t0 - 6 + c;
            float v = 0.f;
            if (gc >= 0 && gc < TT) v = a[(i0 + h * 32 + r) * TT + gc];
            smem[r * 76 + c] = v;
        }
        __syncthreads();
        if (interior) {
            for (int r = ig; r < 32; r += 4) {
                float xx = smem[r * 76 + tl + 6];
#pragma unroll
                for (int k = 0; k < 11; ++k) {
                    float d = xx - smem[r * 76 + tl + k];
                    acc[k] += d * d;
                }
            }
        } else {
            const int t = t0 + tl;
            if (t < TT) {
                for (int r = ig; r < 32; r += 4) {
                    float xx = smem[r * 76 + tl + 6];
#pragma unroll
                    for (int k = 0; k < 11; ++k) {
                        int q = t + k - 6;
                        float d = xx - smem[r * 76 + tl + k];
                        if (q >= 0 && q < TT) acc[k] += d * d;
                    }
                }
            }
        }
        __syncthreads();   // tile reads done before next-half overwrite / red aliasing
    }

#pragma unroll
    for (int k = 0; k < 11; ++k) smem[ig * 704 + tl * 11 + k] = acc[k];
    __syncthreads();

    // transposed store: ns_p[(x*704 + l)*64 + y]
    for (int l = tid; l < 704; l += 256) {
        float s = smem[l] + smem[704 + l] + smem[1408 + l] + smem[2112 + l];
        ns_p[(size_t)(x * 704 + l) * 64 + y] = s;
    }

    // folded edge work: blocks 0..123 -> pair q = b>>2, i-chunk ch = b&3
    if (b < 124) {
        const int q = b >> 2, ch = b & 3;
        int t = 0, k = 0;
        if (q < 21) {                       // front: t+k < 6, t-major
            int idx = q;
            for (int tt = 0; tt < 6; ++tt) {
                int c = 6 - tt;
                if (idx < c) { t = tt; k = idx; break; }
                idx -= c;
            }
        } else {                            // back: t+k >= 756
            int idx = q - 21;
            for (int tt = 746; tt < 750; ++tt) {
                int c = tt - 745;
                if (idx < c) { t = tt; k = (11 - c) + idx; break; }
                idx -= c;
            }
        }
        const int p = t + k;                // block-uniform
        float s = 0.f;
        int i = ch * 1024 + tid;
#pragma unroll
        for (int it = 0; it < 4; ++it, i += 256) {
            float xv = a[i * TT + t];
            float v = (p < 6) ? a[((6 * i + p) & (BB - 1)) * TT]
                              : a[((6 * i + (p - 755)) & (BB - 1)) * TT + (TT - 1)];
            float d = xv - v;
            s += d * d;
        }
        for (int off = 32; off > 0; off >>= 1) s += __shfl_down(s, off, 64);
        if ((tid & 63) == 0) swred[tid >> 6] = s;
        __syncthreads();
        if (tid == 0)
            edge_c[q * 4 + ch] = swred[0] + swred[1] + swred[2] + swred[3];
    }
}

// ============ node 1: phase1 ============
__global__ __launch_bounds__(256, 4) void k_A(const float* __restrict__ a,
                                              float* __restrict__ ws) {
    phase1(a, ws + NSP_OFF, ws + EDGE_OFF, blockIdx.x, threadIdx.x);
}

// ============ node 2: reduce 64 y-partials (float4) + edge, exp, per-block k!=6 flag ====
// ns[t,6] == 0 structurally (window center) -> ens[t,6] == 1 always; but d2[:,:,6] == 0
// structurally too, so k=6 can never contribute -> flag excludes k==6 (verified R8).
__global__ __launch_bounds__(256) void k_B(const float* __restrict__ ws_ro,
                                           float* __restrict__ ws) {
    const float* ns_p   = ws_ro + NSP_OFF;
    const float* edge_c = ws_ro + EDGE_OFF;
    float* ens   = ws + ENS_OFF;
    int*   flags = (int*)(ws + FLAG_OFF);
    __shared__ int swf[4];
    const int b = blockIdx.x, tid = threadIdx.x;
    const int l = b * 256 + tid;
    const int k = l / NS_STRIDE;
    const int t = l - k * NS_STRIDE;
    float e = 0.f;
    if (t < TT) {
        const int idx2 = (t >> 6) * 704 + (t & 63) * 11 + k;
        const float4* pp4 = (const float4*)(ns_p + (size_t)idx2 * 64);
        float s = 0.f;
#pragma unroll
        for (int j = 0; j < 16; ++j) {
            float4 v = pp4[j];
            s += v.x + v.y + v.z + v.w;
        }
        const int p = t + k;
        if (p < 6 || p >= 756) {
            int idx = (p < 6) ? (t * 6 - t * (t - 1) / 2 + k)
                              : (21 + (t - 746) * (t - 745) / 2 + (k - (756 - t)));
            s += edge_c[idx * 4 + 0] + edge_c[idx * 4 + 1] +
                 edge_c[idx * 4 + 2] + edge_c[idx * 4 + 3];
        }
        e = __expf(-0.5f * s);
    }
    ens[l] = e;
    unsigned long long anyb = __ballot(e > 0.f && k != 6);
    if ((tid & 63) == 0) swf[tid >> 6] = (anyb != 0ull);
    __syncthreads();
    if (tid == 0) flags[b] = swf[0] | swf[1] | swf[2] | swf[3];
}

// ============ node 3: main loss (16 i's per block), plain slot store, NO epilogue =======
// R8 lesson: __threadfence + device atomics in a 768-block kernel cost ~65 us of idle;
// stream-ordered dispatch boundaries are the cheap ordering primitive on MI355X.
__global__ __launch_bounds__(256, 4) void k_C(const float* __restrict__ a,
                                              const float* __restrict__ a2,
                                              float* __restrict__ ws,
                                              float* __restrict__ out_unused) {
    const float* ens   = ws + ENS_OFF;
    const int*   flags = (const int*)(ws + FLAG_OFF);
    float* slots = ws + SLOT_OFF;
    __shared__ float s_a4[268];
    __shared__ float s_a3[268];
    __shared__ float swred[4];
    const int b = blockIdx.x, tid = threadIdx.x;
    const int x = b % 3;            // t-chunk
    const int y = b / 3;            // i-group
    const int t0 = x * 256;
    const int t = t0 + tid;

    int flag = 0;
    for (int j = 0; j < NRED; ++j) flag |= flags[j];   // uniform, cross-kernel visible

    float partial = 0.f;
    if (flag == 0) {
        // all ens (k!=6) are zero; k=6 term structurally zero -> only the reg term
        if (t < TT) {
            float s = 0.f;
#pragma unroll
            for (int ii = 0; ii < 16; ++ii) {
                int i = y * 16 + ii;
                float d = a[i * TT + t] - a2[i * TT + t];
                s += d * d;
            }
            partial = 0.1f * s;                        // E_THETA
        }
    } else {
        // general path (verified R4-R8); its k=6 term multiplies d2==0, harmless
        for (int ii = 0; ii < 16; ++ii) {
            const int i = y * 16 + ii;
            __syncthreads();
            for (int c = tid; c < 266; c += 256) {
                int p = t0 + c;
                float v4, v3;
                if (p < 6) {
                    int r = (6 * i + p) & (BB - 1);
                    v4 = a[r * TT];
                    v3 = a2[r * TT];
                } else if (p < 756) {
                    v4 = a[i * TT + p - 6];
                    v3 = a2[i * TT + p - 6];
                } else {
                    int r = (6 * i + (p - 755)) & (BB - 1);
                    v4 = a[r * TT + (TT - 1)];
                    v3 = a2[r * TT + (TT - 1)];
                }
                s_a4[c] = v4;
                s_a3[c] = v3;
            }
            __syncthreads();
            if (t < TT) {
                const float s1 = s_a4[tid + 6];
                const float s2 = s_a3[tid + 6];
                float mw = -1e30f;
                float acc_d[11], acc_e[11];
#pragma unroll
                for (int k = 0; k < 11; ++k) {
                    float a4v = s_a4[tid + k];
                    float a3v = s_a3[tid + k];
                    int rr = (11 * i + k) & (BB - 1);
                    float tv = a[rr * TT + t];
                    mw = fmaxf(mw, tv - a4v);
                    acc_d[k] = fabsf(s2 - a3v);
                    acc_e[k] = ens[k * NS_STRIDE + t];
                }
                float g = mw * mw;                     // E_G
                float eg = __expf(-0.5f * g);          // SIGMA
                float acc = 0.f;
#pragma unroll
                for (int k = 0; k < 11; ++k) acc += fminf(acc_e[k], eg) * acc_d[k];
                float diff = s1 - s2;
                partial += acc + 0.1f * diff * diff;
            }
        }
    }

    for (int off = 32; off > 0; off >>= 1) partial += __shfl_down(partial, off, 64);
    if ((tid & 63) == 0) swred[tid >> 6] = partial;
    __syncthreads();
    if (tid == 0)
        slots[b] = swred[0] + swred[1] + swred[2] + swred[3];   // plain store, done
}

// ============ node 4: final reduce of 768 slots ============
__global__ __launch_bounds__(256) void k_D(const float* __restrict__ ws_ro,
                                           float* __restrict__ out) {
    const float* slots = ws_ro + SLOT_OFF;
    __shared__ float fred[4];
    const int tid = threadIdx.x;
    float v = slots[tid] + slots[tid + 256] + slots[tid + 512];
    for (int off = 32; off > 0; off >>= 1) v += __shfl_down(v, off, 64);
    if ((tid & 63) == 0) fred[tid >> 6] = v;
    __syncthreads();
    if (tid == 0)
        out[0] = (fred[0] + fred[1] + fred[2] + fred[3]) * (1.0f / BB);  // E_ALPHA
}

extern "C" void kernel_launch(void* const* d_in, const int* in_sizes, int n_in,
                              void* d_out, int out_size, void* d_ws, size_t ws_size,
                              hipStream_t stream) {
    const float* a  = (const float*)d_in[0];   // actioness
    const float* a2 = (const float*)d_in[1];   // actioness_2
    float* ws  = (float*)d_ws;
    float* out = (float*)d_out;

    k_A<<<NBLK, 256, 0, stream>>>(a, ws);
    k_B<<<NRED, 256, 0, stream>>>(ws, ws);
    k_C<<<NBLK, 256, 0, stream>>>(a, a2, ws, out);
    k_D<<<1, 256, 0, stream>>>(ws, out);
}

// Round 10
// 92.217 us; speedup vs baseline: 6.6737x; 1.0210x over previous
//
#include <hip/hip_runtime.h>

#define BB 4096
#define TT 750
#define NS_STRIDE 768
#define NBLK 768           // 768 interior tiles; edge pairs folded into blocks 0..123
#define NRED 33            // phase-2 blocks (33*256 = 8448 = 11*768)

// ws float offsets (total < 2.2 MB)
#define NSP_OFF   0                        // 8448*64 transposed interior partials
#define EDGE_OFF  (8448 * 64)              // 124 edge partials (31 pairs x 4 chunks)
#define ENS_OFF   (EDGE_OFF + 128)         // 8448 = exp(-ns/2), layout [k][t] stride 768
#define SLOT_OFF  (ENS_OFF + 8448)         // 768 per-k_C-block window partial sums
#define FLAG_OFF  (SLOT_OFF + 768)         // 33 ints: per-k_B-block any(ens>0 && k!=6)
#define RSLOT_OFF (FLAG_OFF + 64)          // 768 per-k_A-block 0.1*sum(diff^2) partials

// ============ node 1: ns partials + folded edge pairs + reg-term partials ============
// phase1 core verified R6-R9 (absmax 0.0); reg term added here because the a-tile is
// already in LDS -- k_C's fast path then needs no input reads at all.
__global__ __launch_bounds__(256, 4) void k_A(const float* __restrict__ a,
                                              const float* __restrict__ a2,
                                              float* __restrict__ ws) {
    float* ns_p   = ws + NSP_OFF;
    float* edge_c = ws + EDGE_OFF;
    float* rslots = ws + RSLOT_OFF;
    __shared__ float smem[2816];     // halves: tile 32x76 = 2432 ; then red 4x704 = 2816
    __shared__ float swred[4];
    __shared__ float swred2[4];
    const int b = blockIdx.x, tid = threadIdx.x;
    const int x = b % 12, y = b / 12;
    const int t0 = x * 64, i0 = y * 64;
    const int tl = tid & 63, ig = tid >> 6;
    const bool interior = (x >= 1 && x <= 10);

    float acc[11];
#pragma unroll
    for (int k = 0; k < 11; ++k) acc[k] = 0.f;
    float racc = 0.f;                // reg-term accumulator

    for (int h = 0; h < 2; ++h) {
        for (int l = tid; l < 32 * 74; l += 256) {
            int r = l / 74, c = l - r * 74;
            int gc = t0 - 6 + c;
            float v = 0.f;
            if (gc >= 0 && gc < TT) v = a[(i0 + h * 32 + r) * TT + gc];
            smem[r * 76 + c] = v;
        }
        __syncthreads();
        if (interior) {
            for (int r = ig; r < 32; r += 4) {
                float xx = smem[r * 76 + tl + 6];
#pragma unroll
                for (int k = 0; k < 11; ++k) {
                    float d = xx - smem[r * 76 + tl + k];
                    acc[k] += d * d;
                }
            }
        } else {
            const int t = t0 + tl;
            if (t < TT) {
                for (int r = ig; r < 32; r += 4) {
                    float xx = smem[r * 76 + tl + 6];
#pragma unroll
                    for (int k = 0; k < 11; ++k) {
                        int q = t + k - 6;
                        float d = xx - smem[r * 76 + tl + k];
                        if (q >= 0 && q < TT) acc[k] += d * d;
                    }
                }
            }
        }
        // reg term for this half: a[i,t] is a free LDS hit; a2 read is coalesced
        {
            const int t = t0 + tl;
            if (t < TT) {
                for (int r = ig; r < 32; r += 4) {
                    float d = smem[r * 76 + tl + 6] - a2[(i0 + h * 32 + r) * TT + t];
                    racc += d * d;
                }
            }
        }
        __syncthreads();   // tile reads done before next-half overwrite / red aliasing
    }

#pragma unroll
    for (int k = 0; k < 11; ++k) smem[ig * 704 + tl * 11 + k] = acc[k];
    __syncthreads();

    // transposed store: ns_p[(x*704 + l)*64 + y]
    for (int l = tid; l < 704; l += 256) {
        float s = smem[l] + smem[704 + l] + smem[1408 + l] + smem[2112 + l];
        ns_p[(size_t)(x * 704 + l) * 64 + y] = s;
    }

    // reg-term block reduction -> rslots[b] (already scaled by E_THETA)
    for (int off = 32; off > 0; off >>= 1) racc += __shfl_down(racc, off, 64);
    if (tl == 0) swred2[ig] = racc;
    __syncthreads();
    if (tid == 0)
        rslots[b] = 0.1f * (swred2[0] + swred2[1] + swred2[2] + swred2[3]);

    // folded edge work: blocks 0..123 -> pair q = b>>2, i-chunk ch = b&3
    if (b < 124) {
        const int q = b >> 2, ch = b & 3;
        int t = 0, k = 0;
        if (q < 21) {                       // front: t+k < 6, t-major
            int idx = q;
            for (int tt = 0; tt < 6; ++tt) {
                int c = 6 - tt;
                if (idx < c) { t = tt; k = idx; break; }
                idx -= c;
            }
        } else {                            // back: t+k >= 756
            int idx = q - 21;
            for (int tt = 746; tt < 750; ++tt) {
                int c = tt - 745;
                if (idx < c) { t = tt; k = (11 - c) + idx; break; }
                idx -= c;
            }
        }
        const int p = t + k;                // block-uniform
        float s = 0.f;
        int i = ch * 1024 + tid;
#pragma unroll
        for (int it = 0; it < 4; ++it, i += 256) {
            float xv = a[i * TT + t];
            float v = (p < 6) ? a[((6 * i + p) & (BB - 1)) * TT]
                              : a[((6 * i + (p - 755)) & (BB - 1)) * TT + (TT - 1)];
            float d = xv - v;
            s += d * d;
        }
        for (int off = 32; off > 0; off >>= 1) s += __shfl_down(s, off, 64);
        if (tl == 0) swred[ig] = s;
        __syncthreads();
        if (tid == 0)
            edge_c[q * 4 + ch] = swred[0] + swred[1] + swred[2] + swred[3];
    }
}

// ============ node 2: reduce 64 y-partials (float4) + edge, exp, per-block k!=6 flag ====
// ns[t,6] == 0 structurally (window center) -> ens[t,6] == 1 always; but d2[:,:,6] == 0
// structurally too, so k=6 can never contribute -> flag excludes k==6 (verified R8/R9).
__global__ __launch_bounds__(256) void k_B(const float* __restrict__ ws_ro,
                                           float* __restrict__ ws) {
    const float* ns_p   = ws_ro + NSP_OFF;
    const float* edge_c = ws_ro + EDGE_OFF;
    float* ens   = ws + ENS_OFF;
    int*   flags = (int*)(ws + FLAG_OFF);
    __shared__ int swf[4];
    const int b = blockIdx.x, tid = threadIdx.x;
    const int l = b * 256 + tid;
    const int k = l / NS_STRIDE;
    const int t = l - k * NS_STRIDE;
    float e = 0.f;
    if (t < TT) {
        const int idx2 = (t >> 6) * 704 + (t & 63) * 11 + k;
        const float4* pp4 = (const float4*)(ns_p + (size_t)idx2 * 64);
        float s = 0.f;
#pragma unroll
        for (int j = 0; j < 16; ++j) {
            float4 v = pp4[j];
            s += v.x + v.y + v.z + v.w;
        }
        const int p = t + k;
        if (p < 6 || p >= 756) {
            int idx = (p < 6) ? (t * 6 - t * (t - 1) / 2 + k)
                              : (21 + (t - 746) * (t - 745) / 2 + (k - (756 - t)));
            s += edge_c[idx * 4 + 0] + edge_c[idx * 4 + 1] +
                 edge_c[idx * 4 + 2] + edge_c[idx * 4 + 3];
        }
        e = __expf(-0.5f * s);
    }
    ens[l] = e;
    unsigned long long anyb = __ballot(e > 0.f && k != 6);
    if ((tid & 63) == 0) swf[tid >> 6] = (anyb != 0ull);
    __syncthreads();
    if (tid == 0) flags[b] = swf[0] | swf[1] | swf[2] | swf[3];
}

// ============ node 3: window term only (reg term lives in k_A now) ============
__global__ __launch_bounds__(256, 4) void k_C(const float* __restrict__ a,
                                              const float* __restrict__ a2,
                                              float* __restrict__ ws) {
    const float* ens   = ws + ENS_OFF;
    const int*   flags = (const int*)(ws + FLAG_OFF);
    float* slots = ws + SLOT_OFF;
    const int b = blockIdx.x, tid = threadIdx.x;

    int flag = 0;
    for (int j = 0; j < NRED; ++j) flag |= flags[j];   // uniform, cross-kernel visible

    if (flag == 0) {
        // all ens (k!=6) zero; k=6 term structurally zero; reg term in k_A -> nothing here
        if (tid == 0) slots[b] = 0.f;
        return;
    }

    __shared__ float s_a4[268];
    __shared__ float s_a3[268];
    __shared__ float swred[4];
    const int x = b % 3;            // t-chunk
    const int y = b / 3;            // i-group
    const int t0 = x * 256;
    const int t = t0 + tid;

    float partial = 0.f;
    // general path (verified R4-R9, minus the reg term); k=6 term multiplies d2==0
    for (int ii = 0; ii < 16; ++ii) {
        const int i = y * 16 + ii;
        __syncthreads();
        for (int c = tid; c < 266; c += 256) {
            int p = t0 + c;
            float v4, v3;
            if (p < 6) {
                int r = (6 * i + p) & (BB - 1);
                v4 = a[r * TT];
                v3 = a2[r * TT];
            } else if (p < 756) {
                v4 = a[i * TT + p - 6];
                v3 = a2[i * TT + p - 6];
            } else {
                int r = (6 * i + (p - 755)) & (BB - 1);
                v4 = a[r * TT + (TT - 1)];
                v3 = a2[r * TT + (TT - 1)];
            }
            s_a4[c] = v4;
            s_a3[c] = v3;
        }
        __syncthreads();
        if (t < TT) {
            const float s2 = s_a3[tid + 6];
            float mw = -1e30f;
            float acc_d[11], acc_e[11];
#pragma unroll
            for (int k = 0; k < 11; ++k) {
                float a4v = s_a4[tid + k];
                float a3v = s_a3[tid + k];
                int rr = (11 * i + k) & (BB - 1);
                float tv = a[rr * TT + t];
                mw = fmaxf(mw, tv - a4v);
                acc_d[k] = fabsf(s2 - a3v);
                acc_e[k] = ens[k * NS_STRIDE + t];
            }
            float g = mw * mw;                     // E_G
            float eg = __expf(-0.5f * g);          // SIGMA
            float acc = 0.f;
#pragma unroll
            for (int k = 0; k < 11; ++k) acc += fminf(acc_e[k], eg) * acc_d[k];
            partial += acc;
        }
    }

    for (int off = 32; off > 0; off >>= 1) partial += __shfl_down(partial, off, 64);
    if ((tid & 63) == 0) swred[tid >> 6] = partial;
    __syncthreads();
    if (tid == 0)
        slots[b] = swred[0] + swred[1] + swred[2] + swred[3];   // plain store, done
}

// ============ node 4: final reduce of window slots + reg slots ============
__global__ __launch_bounds__(256) void k_D(const float* __restrict__ ws_ro,
                                           float* __restrict__ out) {
    const float* slots  = ws_ro + SLOT_OFF;
    const float* rslots = ws_ro + RSLOT_OFF;
    __shared__ float fred[4];
    const int tid = threadIdx.x;
    float v = slots[tid] + slots[tid + 256] + slots[tid + 512]
            + rslots[tid] + rslots[tid + 256] + rslots[tid + 512];
    for (int off = 32; off > 0; off >>= 1) v += __shfl_down(v, off, 64);
    if ((tid & 63) == 0) fred[tid >> 6] = v;
    __syncthreads();
    if (tid == 0)
        out[0] = (fred[0] + fred[1] + fred[2] + fred[3]) * (1.0f / BB);  // E_ALPHA
}

extern "C" void kernel_launch(void* const* d_in, const int* in_sizes, int n_in,
                              void* d_out, int out_size, void* d_ws, size_t ws_size,
                              hipStream_t stream) {
    const float* a  = (const float*)d_in[0];   // actioness
    const float* a2 = (const float*)d_in[1];   // actioness_2
    float* ws  = (float*)d_ws;
    float* out = (float*)d_out;

    k_A<<<NBLK, 256, 0, stream>>>(a, a2, ws);
    k_B<<<NRED, 256, 0, stream>>>(ws, ws);
    k_C<<<NBLK, 256, 0, stream>>>(a, a2, ws);
    k_D<<<1, 256, 0, stream>>>(ws, out);
}

// Round 11
// 90.190 us; speedup vs baseline: 6.8236x; 1.0225x over previous
//
#include <hip/hip_runtime.h>

#define BB 4096
#define TT 750
#define NS_STRIDE 768
#define NBLK 768           // 768 interior tiles; edge pairs folded into blocks 0..123
#define NRED 33            // phase-2 blocks (33*256 = 8448 = 11*768)

// ws float offsets (total < 1.3 MB)
// SYMMETRY: ns[t,k] = ns[t+k-6, 12-k], so k_A only computes k in [0,5] (k=6 is 0).
// ns_p rows per x-tile: 64 t * 6 k = 384.
#define NSP_OFF   0                        // 12*384*64 transposed interior partials
#define EDGE_OFF  (4608 * 64)              // 124 edge partials (31 pairs x 4 chunks)
#define ENS_OFF   (EDGE_OFF + 128)         // 8448 = exp(-ns/2), layout [k][t] stride 768
#define SLOT_OFF  (ENS_OFF + 8448)         // 768 per-k_C-block window partial sums
#define FLAG_OFF  (SLOT_OFF + 768)         // 33 ints: per-k_B-block any(ens>0 && k!=6)
#define RSLOT_OFF (FLAG_OFF + 64)          // 768 per-k_A-block 0.1*sum(diff^2) partials

// ============ node 1: ns partials (k<6 only) + folded edge pairs + reg term ============
__global__ __launch_bounds__(256, 4) void k_A(const float* __restrict__ a,
                                              const float* __restrict__ a2,
                                              float* __restrict__ ws) {
    float* ns_p   = ws + NSP_OFF;
    float* edge_c = ws + EDGE_OFF;
    float* rslots = ws + RSLOT_OFF;
    __shared__ float smem[2432];     // tile 32x76 = 2432; reduction reuses [0,1536)
    __shared__ float swred[4];
    __shared__ float swred2[4];
    const int b = blockIdx.x, tid = threadIdx.x;
    const int x = b % 12, y = b / 12;
    const int t0 = x * 64, i0 = y * 64;
    const int tl = tid & 63, ig = tid >> 6;

    float acc[6] = {0.f, 0.f, 0.f, 0.f, 0.f, 0.f};
    float racc = 0.f;                // reg-term accumulator

    for (int h = 0; h < 2; ++h) {
        for (int l = tid; l < 32 * 74; l += 256) {
            int r = l / 74, c = l - r * 74;
            int gc = t0 - 6 + c;
            float v = 0.f;
            if (gc >= 0 && gc < TT) v = a[(i0 + h * 32 + r) * TT + gc];
            smem[r * 76 + c] = v;
        }
        __syncthreads();
        // window loop, k in [0,5] only (q = t+k-6 in [t-6, t-1])
        if (x == 0) {
            // front tile: guard q >= 0  (q < TT impossible: q <= 57)
            for (int r = ig; r < 32; r += 4) {
                float xx = smem[r * 76 + tl + 6];
#pragma unroll
                for (int k = 0; k < 6; ++k) {
                    float d = xx - smem[r * 76 + tl + k];
                    if (tl + k >= 6) acc[k] += d * d;
                }
            }
        } else if (x == 11) {
            // back tile: t >= 704; q <= 748 < TT always; only t < TT guard
            const int t = t0 + tl;
            if (t < TT) {
                for (int r = ig; r < 32; r += 4) {
                    float xx = smem[r * 76 + tl + 6];
#pragma unroll
                    for (int k = 0; k < 6; ++k) {
                        float d = xx - smem[r * 76 + tl + k];
                        acc[k] += d * d;
                    }
                }
            }
        } else {
            // interior: no guards
            for (int r = ig; r < 32; r += 4) {
                float xx = smem[r * 76 + tl + 6];
#pragma unroll
                for (int k = 0; k < 6; ++k) {
                    float d = xx - smem[r * 76 + tl + k];
                    acc[k] += d * d;
                }
            }
        }
        // reg term: a[i,t] is a free LDS hit; a2 read coalesced
        {
            const int t = t0 + tl;
            if (t < TT) {
                for (int r = ig; r < 32; r += 4) {
                    float d = smem[r * 76 + tl + 6] - a2[(i0 + h * 32 + r) * TT + t];
                    racc += d * d;
                }
            }
        }
        __syncthreads();   // tile reads done before next-half overwrite / red aliasing
    }

    // reduction buffer aliases smem: red[ig][tl*6 + k], 4*384 = 1536 floats
#pragma unroll
    for (int k = 0; k < 6; ++k) smem[ig * 384 + tl * 6 + k] = acc[k];
    __syncthreads();

    // transposed store: ns_p[(x*384 + l)*64 + y]
    for (int l = tid; l < 384; l += 256) {
        float s = smem[l] + smem[384 + l] + smem[768 + l] + smem[1152 + l];
        ns_p[(size_t)(x * 384 + l) * 64 + y] = s;
    }

    // reg-term block reduction -> rslots[b] (already scaled by E_THETA)
    for (int off = 32; off > 0; off >>= 1) racc += __shfl_down(racc, off, 64);
    if (tl == 0) swred2[ig] = racc;
    __syncthreads();
    if (tid == 0)
        rslots[b] = 0.1f * (swred2[0] + swred2[1] + swred2[2] + swred2[3]);

    // folded edge work: blocks 0..123 -> pair q = b>>2, i-chunk ch = b&3 (verified R6-R10)
    if (b < 124) {
        const int q = b >> 2, ch = b & 3;
        int t = 0, k = 0;
        if (q < 21) {                       // front: t+k < 6, t-major
            int idx = q;
            for (int tt = 0; tt < 6; ++tt) {
                int c = 6 - tt;
                if (idx < c) { t = tt; k = idx; break; }
                idx -= c;
            }
        } else {                            // back: t+k >= 756
            int idx = q - 21;
            for (int tt = 746; tt < 750; ++tt) {
                int c = tt - 745;
                if (idx < c) { t = tt; k = (11 - c) + idx; break; }
                idx -= c;
            }
        }
        const int p = t + k;                // block-uniform
        float s = 0.f;
        int i = ch * 1024 + tid;
#pragma unroll
        for (int it = 0; it < 4; ++it, i += 256) {
            float xv = a[i * TT + t];
            float v = (p < 6) ? a[((6 * i + p) & (BB - 1)) * TT]
                              : a[((6 * i + (p - 755)) & (BB - 1)) * TT + (TT - 1)];
            float d = xv - v;
            s += d * d;
        }
        for (int off = 32; off > 0; off >>= 1) s += __shfl_down(s, off, 64);
        if (tl == 0) swred[ig] = s;
        __syncthreads();
        if (tid == 0)
            edge_c[q * 4 + ch] = swred[0] + swred[1] + swred[2] + swred[3];
    }
}

// ============ node 2: row-sum (mirror-aware) + edge, exp, per-block k!=6 flag ============
// k == 6: ns = 0 structurally -> e = 1 (excluded from flag; its d2 is structurally 0).
// k <  6: direct row (t, k); possible front edge (p < 6).
// k >= 7: mirror row (q = t+k-6, 12-k); possible back edge (p >= 756, where the mirror
//         row lies in the guard-zeroed t>=750 region of tile 11 and edge_c completes it).
__global__ __launch_bounds__(256) void k_B(const float* __restrict__ ws_ro,
                                           float* __restrict__ ws) {
    const float* ns_p   = ws_ro + NSP_OFF;
    const float* edge_c = ws_ro + EDGE_OFF;
    float* ens   = ws + ENS_OFF;
    int*   flags = (int*)(ws + FLAG_OFF);
    __shared__ int swf[4];
    const int b = blockIdx.x, tid = threadIdx.x;
    const int l = b * 256 + tid;
    const int k = l / NS_STRIDE;
    const int t = l - k * NS_STRIDE;
    float e = 0.f;
    if (t < TT) {
        if (k == 6) {
            e = 1.0f;
        } else {
            int row;
            if (k < 6) {
                row = (t >> 6) * 384 + (t & 63) * 6 + k;
            } else {
                int q = t + k - 6;          // <= 753 < 768, rows >= 750 are zero
                int kk = 12 - k;            // in [2,5]
                row = (q >> 6) * 384 + (q & 63) * 6 + kk;
            }
            const float4* pp4 = (const float4*)(ns_p + (size_t)row * 64);
            float s = 0.f;
#pragma unroll
            for (int j = 0; j < 16; ++j) {
                float4 v = pp4[j];
                s += v.x + v.y + v.z + v.w;
            }
            const int p = t + k;
            if (p < 6) {                    // only possible for k < 6
                int idx = t * 6 - t * (t - 1) / 2 + k;
                s += edge_c[idx * 4 + 0] + edge_c[idx * 4 + 1] +
                     edge_c[idx * 4 + 2] + edge_c[idx * 4 + 3];
            } else if (p >= 756) {          // only possible for k >= 7
                int idx = 21 + (t - 746) * (t - 745) / 2 + (k - (756 - t));
                s += edge_c[idx * 4 + 0] + edge_c[idx * 4 + 1] +
                     edge_c[idx * 4 + 2] + edge_c[idx * 4 + 3];
            }
            e = __expf(-0.5f * s);
        }
    }
    ens[l] = e;
    unsigned long long anyb = __ballot(e > 0.f && k != 6);
    if ((tid & 63) == 0) swf[tid >> 6] = (anyb != 0ull);
    __syncthreads();
    if (tid == 0) flags[b] = swf[0] | swf[1] | swf[2] | swf[3];
}

// ============ node 3: window term only (reg term lives in k_A) — unchanged R10 ==========
__global__ __launch_bounds__(256, 4) void k_C(const float* __restrict__ a,
                                              const float* __restrict__ a2,
                                              float* __restrict__ ws) {
    const float* ens   = ws + ENS_OFF;
    const int*   flags = (const int*)(ws + FLAG_OFF);
    float* slots = ws + SLOT_OFF;
    const int b = blockIdx.x, tid = threadIdx.x;

    int flag = 0;
    for (int j = 0; j < NRED; ++j) flag |= flags[j];   // uniform, cross-kernel visible

    if (flag == 0) {
        // all ens (k!=6) zero; k=6 term structurally zero; reg term in k_A -> nothing here
        if (tid == 0) slots[b] = 0.f;
        return;
    }

    __shared__ float s_a4[268];
    __shared__ float s_a3[268];
    __shared__ float swred[4];
    const int x = b % 3;            // t-chunk
    const int y = b / 3;            // i-group
    const int t0 = x * 256;
    const int t = t0 + tid;

    float partial = 0.f;
    // general path (verified R4-R10, reg term removed); k=6 term multiplies d2==0
    for (int ii = 0; ii < 16; ++ii) {
        const int i = y * 16 + ii;
        __syncthreads();
        for (int c = tid; c < 266; c += 256) {
            int p = t0 + c;
            float v4, v3;
            if (p < 6) {
                int r = (6 * i + p) & (BB - 1);
                v4 = a[r * TT];
                v3 = a2[r * TT];
            } else if (p < 756) {
                v4 = a[i * TT + p - 6];
                v3 = a2[i * TT + p - 6];
            } else {
                int r = (6 * i + (p - 755)) & (BB - 1);
                v4 = a[r * TT + (TT - 1)];
                v3 = a2[r * TT + (TT - 1)];
            }
            s_a4[c] = v4;
            s_a3[c] = v3;
        }
        __syncthreads();
        if (t < TT) {
            const float s2 = s_a3[tid + 6];
            float mw = -1e30f;
            float acc_d[11], acc_e[11];
#pragma unroll
            for (int k = 0; k < 11; ++k) {
                float a4v = s_a4[tid + k];
                float a3v = s_a3[tid + k];
                int rr = (11 * i + k) & (BB - 1);
                float tv = a[rr * TT + t];
                mw = fmaxf(mw, tv - a4v);
                acc_d[k] = fabsf(s2 - a3v);
                acc_e[k] = ens[k * NS_STRIDE + t];
            }
            float g = mw * mw;                     // E_G
            float eg = __expf(-0.5f * g);          // SIGMA
            float acc = 0.f;
#pragma unroll
            for (int k = 0; k < 11; ++k) acc += fminf(acc_e[k], eg) * acc_d[k];
            partial += acc;
        }
    }

    for (int off = 32; off > 0; off >>= 1) partial += __shfl_down(partial, off, 64);
    if ((tid & 63) == 0) swred[tid >> 6] = partial;
    __syncthreads();
    if (tid == 0)
        slots[b] = swred[0] + swred[1] + swred[2] + swred[3];   // plain store, done
}

// ============ node 4: final reduce of window slots + reg slots — unchanged R10 ==========
__global__ __launch_bounds__(256) void k_D(const float* __restrict__ ws_ro,
                                           float* __restrict__ out) {
    const float* slots  = ws_ro + SLOT_OFF;
    const float* rslots = ws_ro + RSLOT_OFF;
    __shared__ float fred[4];
    const int tid = threadIdx.x;
    float v = slots[tid] + slots[tid + 256] + slots[tid + 512]
            + rslots[tid] + rslots[tid + 256] + rslots[tid + 512];
    for (int off = 32; off > 0; off >>= 1) v += __shfl_down(v, off, 64);
    if ((tid & 63) == 0) fred[tid >> 6] = v;
    __syncthreads();
    if (tid == 0)
        out[0] = (fred[0] + fred[1] + fred[2] + fred[3]) * (1.0f / BB);  // E_ALPHA
}

extern "C" void kernel_launch(void* const* d_in, const int* in_sizes, int n_in,
                              void* d_out, int out_size, void* d_ws, size_t ws_size,
                              hipStream_t stream) {
    const float* a  = (const float*)d_in[0];   // actioness
    const float* a2 = (const float*)d_in[1];   // actioness_2
    float* ws  = (float*)d_ws;
    float* out = (float*)d_out;

    k_A<<<NBLK, 256, 0, stream>>>(a, a2, ws);
    k_B<<<NRED, 256, 0, stream>>>(ws, ws);
    k_C<<<NBLK, 256, 0, stream>>>(a, a2, ws);
    k_D<<<1, 256, 0, stream>>>(ws, out);
}